// Round 2
// baseline (2766.881 us; speedup 1.0000x reference)
//
#include <hip/hip_runtime.h>
#include <math.h>
#include <stdint.h>

// Problem constants
#define Bn 32
#define Sn 512
#define En 256
#define Hn 512
#define Ln 48
#define G4 2048   // 4*H
#define NWG 32    // workgroups in lstm_rec (fused fwd+bwd)
#define SENT16 0x7FFFu   // bf16 NaN — impossible for h = o*tanh(c), |h|<1

typedef unsigned short u16;
typedef __attribute__((ext_vector_type(8))) __bf16 bf16x8;
typedef __attribute__((ext_vector_type(4))) float f32x4;

__device__ inline float bf2f(u16 u) {
    return __uint_as_float(((unsigned)u) << 16);
}
__device__ inline u16 f2bf(float f) {
    unsigned u = __float_as_uint(f);
    unsigned r = (u + 0x7fffu + ((u >> 16) & 1u)) >> 16;  // RTNE
    return (u16)r;
}
__device__ inline float sigmoidf_(float x) { return 1.f / (1.f + expf(-x)); }
__device__ inline float tanh_fast(float x) { return 2.f / (1.f + expf(-2.f * x)) - 1.f; }

// any 16-bit field of the 4 dwords equals SENT16?
__device__ inline unsigned badMask(f32x4 v) {
    unsigned acc = 0;
    #pragma unroll
    for (int i = 0; i < 4; i++) {
        unsigned d = __float_as_uint(v[i]);
        unsigned x = d ^ 0x7FFF7FFFu;
        acc |= (x - 0x00010001u) & ~x & 0x80008000u;
    }
    return acc;
}

// Raw barrier: LDS-producer/consumer safe (lgkmcnt(0)), does NOT drain vmcnt
// — in-flight global_load_lds prefetches survive it.
__device__ inline void wg_barrier() {
    asm volatile("s_waitcnt lgkmcnt(0)" ::: "memory");
    __builtin_amdgcn_s_barrier();
    asm volatile("" ::: "memory");
}
// Phase-top barrier: drains vmcnt too (prefetched LDS data valid after this).
__device__ inline void wg_barrier_vm() {
    asm volatile("s_waitcnt vmcnt(0) lgkmcnt(0)" ::: "memory");
    __builtin_amdgcn_s_barrier();
    asm volatile("" ::: "memory");
}

// async global->LDS 16B per lane; aux=17 (sc0|sc1 device-scope read)
__device__ inline void gl_lds16(const u16* gsrc, u16* ldst) {
    __builtin_amdgcn_global_load_lds(
        (const __attribute__((address_space(1))) unsigned int*)gsrc,
        (__attribute__((address_space(3))) unsigned int*)ldst,
        16, 0, 17);
}

// Owner-check of this thread's 4 swizzled LDS slots; rare fallback = proven
// R8-style fused issue+wait sentinel poll (register lifetime contained in one
// asm block — no split-issue hazard).
__device__ inline void check_fix(u16* Hsbuf, const u16* rowbase, int b, int hc) {
    int sw = b & 7;
    u16* s0 = &Hsbuf[(b * 64 + (hc + 0)) * 8];
    u16* s1 = &Hsbuf[(b * 64 + (hc + 16)) * 8];
    u16* s2 = &Hsbuf[(b * 64 + (hc + 32)) * 8];
    u16* s3 = &Hsbuf[(b * 64 + (hc + 48)) * 8];
    f32x4 h0 = *(const f32x4*)s0;
    f32x4 h1 = *(const f32x4*)s1;
    f32x4 h2 = *(const f32x4*)s2;
    f32x4 h3 = *(const f32x4*)s3;
    if (badMask(h0) | badMask(h1) | badMask(h2) | badMask(h3)) {
        const u16* p0 = rowbase + (size_t)((hc + 0) ^ sw) * 8;
        const u16* p1 = rowbase + (size_t)((hc + 16) ^ sw) * 8;
        const u16* p2 = rowbase + (size_t)((hc + 32) ^ sw) * 8;
        const u16* p3 = rowbase + (size_t)((hc + 48) ^ sw) * 8;
        int tries = 0;
        for (;;) {
            asm volatile(
                "global_load_dwordx4 %0, %4, off sc1\n\t"
                "global_load_dwordx4 %1, %5, off sc1\n\t"
                "global_load_dwordx4 %2, %6, off sc1\n\t"
                "global_load_dwordx4 %3, %7, off sc1\n\t"
                "s_waitcnt vmcnt(0)"
                : "=&v"(h0), "=&v"(h1), "=&v"(h2), "=&v"(h3)
                : "v"(p0), "v"(p1), "v"(p2), "v"(p3)
                : "memory");
            if (!(badMask(h0) | badMask(h1) | badMask(h2) | badMask(h3))) break;
            if (++tries > (1 << 16)) break;   // fail-safe: never hang
        }
        *(f32x4*)s0 = h0; *(f32x4*)s1 = h1; *(f32x4*)s2 = h2; *(f32x4*)s3 = h3;
    }
}

// ---------------------------------------------------------------------------
// prep: embed gather -> bf16 x, weight bf16 conversions, exp(T), zero accums,
// sentinel-fill h buffers
// ---------------------------------------------------------------------------
__global__ __launch_bounds__(256) void prep_kernel(
    const int* __restrict__ tokens, const float* __restrict__ embed,
    const float* __restrict__ wihf, const float* __restrict__ wihb,
    const float* __restrict__ whhf, const float* __restrict__ whhb,
    const float* __restrict__ wem, const float* __restrict__ trans,
    u16* __restrict__ xbf, u16* __restrict__ wihf_b, u16* __restrict__ wihb_b,
    u16* __restrict__ whhf_b, u16* __restrict__ whhb_b, u16* __restrict__ wem_b,
    float* __restrict__ expT, float* __restrict__ alphaAcc,
    float* __restrict__ realAcc, unsigned* __restrict__ hf32,
    unsigned* __restrict__ hb32)
{
    size_t idx = (size_t)blockIdx.x * blockDim.x + threadIdx.x;
    size_t stride = (size_t)gridDim.x * blockDim.x;
    for (size_t i = idx; i < (size_t)Bn * Sn * En; i += stride) {
        size_t n = i >> 8; int ee = (int)(i & 255);
        int tok = tokens[n];
        xbf[i] = f2bf(embed[(size_t)tok * En + ee]);
    }
    for (size_t i = idx; i < (size_t)G4 * En; i += stride) {
        wihf_b[i] = f2bf(wihf[i]); wihb_b[i] = f2bf(wihb[i]);
    }
    for (size_t i = idx; i < (size_t)G4 * Hn; i += stride) {
        whhf_b[i] = f2bf(whhf[i]); whhb_b[i] = f2bf(whhb[i]);
    }
    for (size_t i = idx; i < (size_t)Ln * 2 * Hn; i += stride) wem_b[i] = f2bf(wem[i]);
    for (size_t i = idx; i < (size_t)Ln * Ln; i += stride) expT[i] = expf(trans[i]);
    for (size_t i = idx; i < (size_t)Bn * Ln; i += stride) alphaAcc[i] = 0.f;
    for (size_t i = idx; i < (size_t)Bn; i += stride) realAcc[i] = 0.f;
    const unsigned sp = (SENT16 << 16) | SENT16;
    for (size_t i = idx; i < (size_t)Bn * Sn * Hn / 2; i += stride) {
        hf32[i] = sp; hb32[i] = sp;
    }
}

// ---------------------------------------------------------------------------
// gemm_xw: xw[dir][t][b][g] = x(b,t) . w_ih[g] + bias[g], bf16 MFMA, fp32 acc
// ---------------------------------------------------------------------------
__global__ __launch_bounds__(256) void gemm_xw(
    const u16* __restrict__ xbf, const u16* __restrict__ wihf_b,
    const u16* __restrict__ wihb_b, const float* __restrict__ bias_f,
    const float* __restrict__ bias_b, u16* __restrict__ xw_f, u16* __restrict__ xw_b)
{
    int mb = blockIdx.x, nb = blockIdx.y, dir = blockIdx.z;
    const u16* wih = dir ? wihb_b : wihf_b;
    const float* bias = dir ? bias_b : bias_f;
    u16* xw = dir ? xw_b : xw_f;

    __shared__ u16 As[128 * 72];   // 128 rows x 64 k, pad 8
    __shared__ u16 Bs[128 * 72];

    int tid = threadIdx.x;
    int w = tid >> 6, lane = tid & 63;
    int lm = lane & 15, kq = lane >> 4;
    int Moff = (w & 1) * 64, Noff = (w >> 1) * 64;

    f32x4 zero = {0.f, 0.f, 0.f, 0.f};
    f32x4 acc[4][4];
    #pragma unroll
    for (int mi = 0; mi < 4; mi++)
        #pragma unroll
        for (int ni = 0; ni < 4; ni++) acc[mi][ni] = zero;

    for (int kc = 0; kc < 4; kc++) {
        #pragma unroll
        for (int it = 0; it < 4; it++) {
            int idx = tid + it * 256;
            int r = idx >> 3, pos = (idx & 7) * 8;
            *(bf16x8*)&As[r * 72 + pos] =
                *(const bf16x8*)&xbf[((size_t)(mb * 128 + r)) * En + kc * 64 + pos];
            *(bf16x8*)&Bs[r * 72 + pos] =
                *(const bf16x8*)&wih[((size_t)(nb * 128 + r)) * En + kc * 64 + pos];
        }
        __syncthreads();
        #pragma unroll
        for (int ks = 0; ks < 2; ks++) {
            int k = ks * 32 + kq * 8;
            bf16x8 af[4], bfr[4];
            #pragma unroll
            for (int mi = 0; mi < 4; mi++)
                af[mi] = *(const bf16x8*)&As[(Moff + mi * 16 + lm) * 72 + k];
            #pragma unroll
            for (int ni = 0; ni < 4; ni++)
                bfr[ni] = *(const bf16x8*)&Bs[(Noff + ni * 16 + lm) * 72 + k];
            #pragma unroll
            for (int mi = 0; mi < 4; mi++)
                #pragma unroll
                for (int ni = 0; ni < 4; ni++)
                    acc[mi][ni] = __builtin_amdgcn_mfma_f32_16x16x32_bf16(
                        af[mi], bfr[ni], acc[mi][ni], 0, 0, 0);
        }
        __syncthreads();
    }
    #pragma unroll
    for (int mi = 0; mi < 4; mi++)
        #pragma unroll
        for (int ni = 0; ni < 4; ni++)
            #pragma unroll
            for (int reg = 0; reg < 4; reg++) {
                int row = Moff + mi * 16 + kq * 4 + reg;
                int col = Noff + ni * 16 + lm;
                int n = mb * 128 + row;          // n = b*512 + t
                int g = nb * 128 + col;
                int t = n & 511, b = n >> 9;
                float v = acc[mi][ni][reg] + bias[g];
                xw[((size_t)t * Bn + b) * G4 + g] = f2bf(v);
            }
}

// ---------------------------------------------------------------------------
// lstm_rec (R10): 32 WGs x 512 thr, cooperative. Each WG owns 16 hidden cols
// of BOTH directions, alternating fwd/bwd phases: each chain's h round-trip
// (sc1 store -> MALL -> prefetch) hides under the other chain's compute.
// Prefetch destination is LDS via global_load_lds (no register in-flight
// state -> no spill hazard). Owner-check vs sentinel at phase top; rare
// fallback = R8's proven single-asm poll. xw gate loads are plain C++ loads
// issued at phase top (compiler-tracked, safe).
// ---------------------------------------------------------------------------
__global__ __launch_bounds__(512) void lstm_rec(
    const u16* __restrict__ whhf_b, const u16* __restrict__ whhb_b,
    const u16* __restrict__ xw_f, const u16* __restrict__ xw_b,
    u16* __restrict__ hf, u16* __restrict__ hb)
{
    int w = blockIdx.x;                 // 16-col slice, shared by both dirs

    __shared__ u16 HsF[32 * 512];       // fwd h_{t-1} staged (swizzled chunks)
    __shared__ u16 HsB[32 * 512];       // bwd h_{t+1} staged
    __shared__ float Cp[4 * 32 * 17];   // gate partials [gate][batch][hcol]
    __shared__ u16 hout[32 * 16];

    int tid = threadIdx.x;
    int wv = tid >> 6, lane = tid & 63;
    int lm = lane & 15, kq = lane >> 4;
    int mt = wv & 1, nt = wv >> 1;       // wave -> (batch-tile, gate)
    int b = tid >> 4, hc = tid & 15;     // gate-phase / staging role

    // B fragments for both directions (w_hh rows for gate nt, cols w*16..+16)
    bf16x8 BfF[16], BfB[16];
    {
        const u16* wrF = &whhf_b[((size_t)nt * Hn + (size_t)w * 16 + lm) * Hn];
        const u16* wrB = &whhb_b[((size_t)nt * Hn + (size_t)w * 16 + lm) * Hn];
        #pragma unroll
        for (int ks = 0; ks < 16; ks++) {
            BfF[ks] = *(const bf16x8*)&wrF[ks * 32 + kq * 8];
            BfB[ks] = *(const bf16x8*)&wrB[ks * 32 + kq * 8];
        }
    }

    float cF = 0.f, cB = 0.f;
    const f32x4 zero = {0.f, 0.f, 0.f, 0.f};

    for (int it = 0; it < Sn; it++) {
        int tf = it, tb = Sn - 1 - it;

        // ============================ FWD phase ============================
        wg_barrier_vm();                 // HsF prefetch (from prev bwd) landed
        if (it > 0)
            check_fix(HsF, &hf[((size_t)b * Sn + (tf - 1)) * Hn], b, hc);
        // fwd xw gates, plain loads (compiler-tracked; waited at use)
        const u16* xpf = &xw_f[((size_t)tf * Bn + b) * G4 + (size_t)w * 16 + hc];
        u16 xg0 = xpf[0 * Hn], xg1 = xpf[1 * Hn], xg2 = xpf[2 * Hn], xg3 = xpf[3 * Hn];
        // prefetch HsB <- hb row tb+1 (consumed by this iteration's bwd phase)
        if (it > 0) {
            #pragma unroll
            for (int c = 0; c < 4; c++) {
                int bb = wv * 4 + c;
                const u16* rowb = &hb[((size_t)bb * Sn + (tb + 1)) * Hn];
                gl_lds16(rowb + (size_t)(lane ^ (bb & 7)) * 8, &HsB[bb * 512]);
            }
        }
        wg_barrier();                                   // bar1: fixes visible
        f32x4 acc = zero;
        if (it > 0) {
            f32x4 aa = zero, ab = zero;
            #pragma unroll
            for (int ks2 = 0; ks2 < 8; ks2++) {
                bf16x8 a0 = *(const bf16x8*)
                    &HsF[((mt * 16 + lm) * 64 + (((2 * ks2) * 4 + kq) ^ (lm & 7))) * 8];
                aa = __builtin_amdgcn_mfma_f32_16x16x32_bf16(a0, BfF[2 * ks2], aa, 0, 0, 0);
                bf16x8 a1 = *(const bf16x8*)
                    &HsF[((mt * 16 + lm) * 64 + (((2 * ks2 + 1) * 4 + kq) ^ (lm & 7))) * 8];
                ab = __builtin_amdgcn_mfma_f32_16x16x32_bf16(a1, BfF[2 * ks2 + 1], ab, 0, 0, 0);
            }
            acc = aa + ab;
        }
        #pragma unroll
        for (int reg = 0; reg < 4; reg++)
            Cp[(nt * 32 + mt * 16 + kq * 4 + reg) * 17 + lm] = acc[reg];
        wg_barrier();                                   // bar2: Cp ready
        {
            float g0 = Cp[(0 * 32 + b) * 17 + hc] + bf2f(xg0);
            float g1 = Cp[(1 * 32 + b) * 17 + hc] + bf2f(xg1);
            float g2 = Cp[(2 * 32 + b) * 17 + hc] + bf2f(xg2);
            float g3 = Cp[(3 * 32 + b) * 17 + hc] + bf2f(xg3);
            float i_ = sigmoidf_(g0);
            float f_ = sigmoidf_(g1);
            float gg = tanh_fast(g2);
            float o_ = sigmoidf_(g3);
            cF = f_ * cF + i_ * gg;
            hout[tid] = f2bf(o_ * tanh_fast(cF));
        }
        wg_barrier();                                   // bar3: hout ready
        if (tid < 64) {                                 // wave 0 stores fwd
            int bq = lane >> 1, half = lane & 1;
            f32x4 hv8 = *(const f32x4*)&hout[lane * 8];
            u16* sp = &hf[((size_t)bq * Sn + tf) * Hn + (size_t)w * 16 + half * 8];
            asm volatile("global_store_dwordx4 %0, %1, off sc1"
                         :: "v"(sp), "v"(hv8) : "memory");
        }

        // ============================ BWD phase ============================
        wg_barrier_vm();                 // HsB prefetch (from fwd phase) landed
        if (it > 0)
            check_fix(HsB, &hb[((size_t)b * Sn + (tb + 1)) * Hn], b, hc);
        // bwd xw gates, plain loads
        const u16* xpb = &xw_b[((size_t)tb * Bn + b) * G4 + (size_t)w * 16 + hc];
        u16 yg0 = xpb[0 * Hn], yg1 = xpb[1 * Hn], yg2 = xpb[2 * Hn], yg3 = xpb[3 * Hn];
        // prefetch HsF <- hf row tf (consumed by next iteration's fwd phase)
        if (it < Sn - 1) {
            #pragma unroll
            for (int c = 0; c < 4; c++) {
                int bb = wv * 4 + c;
                const u16* rowf = &hf[((size_t)bb * Sn + tf) * Hn];
                gl_lds16(rowf + (size_t)(lane ^ (bb & 7)) * 8, &HsF[bb * 512]);
            }
        }
        wg_barrier();                                   // bar1
        acc = zero;
        if (it > 0) {
            f32x4 aa = zero, ab = zero;
            #pragma unroll
            for (int ks2 = 0; ks2 < 8; ks2++) {
                bf16x8 a0 = *(const bf16x8*)
                    &HsB[((mt * 16 + lm) * 64 + (((2 * ks2) * 4 + kq) ^ (lm & 7))) * 8];
                aa = __builtin_amdgcn_mfma_f32_16x16x32_bf16(a0, BfB[2 * ks2], aa, 0, 0, 0);
                bf16x8 a1 = *(const bf16x8*)
                    &HsB[((mt * 16 + lm) * 64 + (((2 * ks2 + 1) * 4 + kq) ^ (lm & 7))) * 8];
                ab = __builtin_amdgcn_mfma_f32_16x16x32_bf16(a1, BfB[2 * ks2 + 1], ab, 0, 0, 0);
            }
            acc = aa + ab;
        }
        #pragma unroll
        for (int reg = 0; reg < 4; reg++)
            Cp[(nt * 32 + mt * 16 + kq * 4 + reg) * 17 + lm] = acc[reg];
        wg_barrier();                                   // bar2
        {
            float g0 = Cp[(0 * 32 + b) * 17 + hc] + bf2f(yg0);
            float g1 = Cp[(1 * 32 + b) * 17 + hc] + bf2f(yg1);
            float g2 = Cp[(2 * 32 + b) * 17 + hc] + bf2f(yg2);
            float g3 = Cp[(3 * 32 + b) * 17 + hc] + bf2f(yg3);
            float i_ = sigmoidf_(g0);
            float f_ = sigmoidf_(g1);
            float gg = tanh_fast(g2);
            float o_ = sigmoidf_(g3);
            cB = f_ * cB + i_ * gg;
            hout[tid] = f2bf(o_ * tanh_fast(cB));
        }
        wg_barrier();                                   // bar3
        if (tid >= 64 && tid < 128) {                   // wave 1 stores bwd
            int bq = lane >> 1, half = lane & 1;
            f32x4 hv8 = *(const f32x4*)&hout[lane * 8];
            u16* sp = &hb[((size_t)bq * Sn + tb) * Hn + (size_t)w * 16 + half * 8];
            asm volatile("global_store_dwordx4 %0, %1, off sc1"
                         :: "v"(sp), "v"(hv8) : "memory");
        }
    }
}

// ---------------------------------------------------------------------------
// emis_crf: fused emission GEMM + exp + CRF accumulation.
// ---------------------------------------------------------------------------
__global__ __launch_bounds__(256) void emis_crf(
    const u16* __restrict__ hf, const u16* __restrict__ hb,
    const u16* __restrict__ wem_b, const float* __restrict__ bem,
    const float* __restrict__ expT, const int* __restrict__ labels,
    const int* __restrict__ lengths, float* __restrict__ e0,
    float* __restrict__ alphaAcc, float* __restrict__ realAcc)
{
    int mb = blockIdx.x;                 // 256 blocks
    int b = mb >> 3, t0 = (mb & 7) * 64; // rows mb*64.. are (b, t0..t0+64)

    __shared__ float eL[64][49];
    __shared__ float Ts[48 * 48];
    __shared__ float sred[4][48];
    __shared__ float rred[64];

    int tid = threadIdx.x;
    for (int i = tid; i < 48 * 48; i += 256) Ts[i] = expT[i];

    int wv = tid >> 6, lane = tid & 63;
    int lm = lane & 15, lkq = (lane >> 4) * 8;
    int row = mb * 64 + wv * 16;

    f32x4 zero = {0.f, 0.f, 0.f, 0.f};
    f32x4 acc[3] = {zero, zero, zero};
    for (int ks = 0; ks < 32; ks++) {
        int k = ks * 32 + lkq;
        const u16* hsrc = (ks < 16) ? &hf[(size_t)(row + lm) * Hn + k]
                                    : &hb[(size_t)(row + lm) * Hn + (k - 512)];
        bf16x8 a = *(const bf16x8*)hsrc;
        #pragma unroll
        for (int nt = 0; nt < 3; nt++) {
            bf16x8 bfr = *(const bf16x8*)&wem_b[(size_t)(nt * 16 + lm) * 1024 + k];
            acc[nt] = __builtin_amdgcn_mfma_f32_16x16x32_bf16(a, bfr, acc[nt], 0, 0, 0);
        }
    }
    #pragma unroll
    for (int nt = 0; nt < 3; nt++)
        #pragma unroll
        for (int reg = 0; reg < 4; reg++) {
            int rib = wv * 16 + (lane >> 4) * 4 + reg;   // row in block = t - t0
            int col = nt * 16 + lm;
            float v = expf(acc[nt][reg] + bem[col]);
            eL[rib][col] = v;
            if ((mb & 7) == 0 && rib == 0) e0[b * Ln + col] = v;   // t == 0
        }
    __syncthreads();

    int len = lengths[b];
    if (tid < 192) {
        int i = tid % 48, tg = tid / 48;   // 4 groups x 48 labels
        float sacc = 0.f;
        for (int p = tg * 16; p < tg * 16 + 16; p++) {
            int t = t0 + p;
            if (t >= 1 && t < len) {
                float m = -1e30f;
                for (int j = 0; j < 48; j++) m = fmaxf(m, Ts[i * 48 + j] + eL[p][j]);
                float s = 0.f;
                for (int j = 0; j < 48; j++) s += expf(Ts[i * 48 + j] + eL[p][j] - m);
                sacc += m + logf(s);
            }
        }
        sred[tg][i] = sacc;
    } else {
        int p = tid - 192;                  // 0..63
        int t = t0 + p;
        float r = 0.f;
        if (t < len) {
            int lab = labels[b * Sn + t];
            r = eL[p][lab];
            if (t >= 1) r += Ts[labels[b * Sn + t - 1] * 48 + lab];
        }
        rred[p] = r;
    }
    __syncthreads();
    if (tid < 48) {
        float s = sred[0][tid] + sred[1][tid] + sred[2][tid] + sred[3][tid];
        atomicAdd(&alphaAcc[b * Ln + tid], s);
    } else if (tid == 48) {
        float r = 0.f;
        for (int p = 0; p < 64; p++) r += rred[p];
        atomicAdd(&realAcc[b], r);
    }
}

__global__ __launch_bounds__(64) void finalize(
    const float* __restrict__ e0, const float* __restrict__ alphaAcc,
    const float* __restrict__ realAcc, float* __restrict__ out)
{
    int b = threadIdx.x;
    if (b >= Bn) return;
    float m = -1e30f;
    for (int i = 0; i < Ln; i++) {
        float a = e0[b * Ln + i] + alphaAcc[b * Ln + i];
        m = fmaxf(m, a);
    }
    float s = 0.f;
    for (int i = 0; i < Ln; i++) {
        float a = e0[b * Ln + i] + alphaAcc[b * Ln + i];
        s += expf(a - m);
    }
    out[b] = m + logf(s) - realAcc[b];
}

// ---------------------------------------------------------------------------
extern "C" void kernel_launch(void* const* d_in, const int* in_sizes, int n_in,
                              void* d_out, int out_size, void* d_ws, size_t ws_size,
                              hipStream_t stream)
{
    const int*   tokens = (const int*)d_in[0];
    const int*   length = (const int*)d_in[1];
    const int*   labels = (const int*)d_in[2];
    const float* embed  = (const float*)d_in[3];
    const float* wihf   = (const float*)d_in[4];
    const float* whhf   = (const float*)d_in[5];
    const float* bf     = (const float*)d_in[6];
    const float* wihb   = (const float*)d_in[7];
    const float* whhb   = (const float*)d_in[8];
    const float* bbv    = (const float*)d_in[9];
    const float* wem    = (const float*)d_in[10];
    const float* bem    = (const float*)d_in[11];
    const float* trans  = (const float*)d_in[12];
    float* out = (float*)d_out;

    char* p = (char*)d_ws;
    auto take = [&](size_t bytes) -> char* {
        char* q = p;
        p += (bytes + 255) & ~(size_t)255;
        return q;
    };
    u16* xw_f   = (u16*)take((size_t)Sn * Bn * G4 * 2);   // 64 MB
    u16* xw_b   = (u16*)take((size_t)Sn * Bn * G4 * 2);   // 64 MB
    u16* hf     = (u16*)take((size_t)Bn * Sn * Hn * 2);   // 16 MB, layout [b][t][k]
    u16* hb     = (u16*)take((size_t)Bn * Sn * Hn * 2);   // 16 MB, layout [b][t][k]
    u16* xbf    = (u16*)take((size_t)Bn * Sn * En * 2);   // 8 MB
    u16* wihf_b = (u16*)take((size_t)G4 * En * 2);
    u16* wihb_b = (u16*)take((size_t)G4 * En * 2);
    u16* whhf_b = (u16*)take((size_t)G4 * Hn * 2);
    u16* whhb_b = (u16*)take((size_t)G4 * Hn * 2);
    u16* wem_b  = (u16*)take((size_t)Ln * 2 * Hn * 2);
    float* expT     = (float*)take((size_t)Ln * Ln * 4);
    float* e0       = (float*)take((size_t)Bn * Ln * 4);
    float* alphaAcc = (float*)take((size_t)Bn * Ln * 4);
    float* realAcc  = (float*)take((size_t)Bn * 4);
    if ((size_t)(p - (char*)d_ws) > ws_size) return;

    prep_kernel<<<4096, 256, 0, stream>>>(tokens, embed, wihf, wihb, whhf, whhb, wem, trans,
                                          xbf, wihf_b, wihb_b, whhf_b, whhb_b, wem_b,
                                          expT, alphaAcc, realAcc,
                                          (unsigned*)hf, (unsigned*)hb);

    dim3 g1(128, 16, 2);
    gemm_xw<<<g1, 256, 0, stream>>>(xbf, wihf_b, wihb_b, bf, bbv, xw_f, xw_b);

    void* ra[] = { (void*)&whhf_b, (void*)&whhb_b, (void*)&xw_f, (void*)&xw_b,
                   (void*)&hf, (void*)&hb };
    hipLaunchCooperativeKernel((const void*)lstm_rec, dim3(NWG), dim3(512), ra, 0, stream);

    emis_crf<<<256, 256, 0, stream>>>(hf, hb, wem_b, bem, expT, labels, length,
                                      e0, alphaAcc, realAcc);
    finalize<<<1, 64, 0, stream>>>(e0, alphaAcc, realAcc, out);
}